// Round 1
// baseline (300.725 us; speedup 1.0000x reference)
//
#include <hip/hip_runtime.h>

typedef unsigned short u16;
typedef unsigned int   u32;
typedef __attribute__((ext_vector_type(8))) __bf16 bf16x8;
typedef __attribute__((ext_vector_type(4))) float  f32x4;

#define AS1q __attribute__((address_space(1)))
#define AS3q __attribute__((address_space(3)))

static __device__ __forceinline__ u16 f2bf(float f) {
    u32 u = __builtin_bit_cast(u32, f);
    u32 r = u + 0x7FFFu + ((u >> 16) & 1u);   // round-to-nearest-even
    return (u16)(r >> 16);
}

static __device__ __forceinline__ bf16x8 ld16(const u16* p) {
    return __builtin_bit_cast(bf16x8, *(const float4*)(const void*)p);
}

static __device__ __forceinline__ f32x4 mfma16(bf16x8 a, bf16x8 b, f32x4 c) {
    return __builtin_amdgcn_mfma_f32_16x16x32_bf16(a, b, c, 0, 0, 0);
}

static __device__ __forceinline__ void gld16(const u16* g, u16* l) {
    __builtin_amdgcn_global_load_lds((const AS1q u32*)g, (AS3q u32*)l, 16, 0, 0);
}

// ---------------- cast x (f32) -> xb (bf16), 4,194,304 elems ----------------
__global__ __launch_bounds__(256) void k_cast_x(const float* __restrict__ x, u16* __restrict__ xb) {
    int i = blockIdx.x * 256 + threadIdx.x;          // over 1,048,576 float4s
    float4 v = ((const float4*)x)[i];
    ushort4 o;
    o.x = f2bf(v.x); o.y = f2bf(v.y); o.z = f2bf(v.z); o.w = f2bf(v.w);
    ((ushort4*)xb)[i] = o;
}

// ---------- transpose+cast: in[K][Nn] f32 -> out[Nn][K] bf16 (dims %32==0) ----------
__global__ __launch_bounds__(256) void k_transpose_cast(const float* __restrict__ in, u16* __restrict__ out,
                                                        int K, int Nn) {
    __shared__ float tile[32][33];
    int tx = threadIdx.x & 31, ty = threadIdx.x >> 5;
    int k0 = blockIdx.y * 32, n0 = blockIdx.x * 32;
#pragma unroll
    for (int i = 0; i < 4; ++i)
        tile[ty + i * 8][tx] = in[(k0 + ty + i * 8) * Nn + n0 + tx];
    __syncthreads();
#pragma unroll
    for (int i = 0; i < 4; ++i)
        out[(n0 + ty + i * 8) * K + k0 + tx] = f2bf(tile[tx][ty + i * 8]);
}

// ---------- shared GEMM pieces: 128x128 tile, BK=64, 4 waves (2x2), XOR-swizzled LDS ----------
// LDS tile: [row 0..127][64 bf16 = 128B]; 16B slot c8 holds data col16 (c8 ^ (row&7)).
static __device__ __forceinline__ void stage128x64(const u16* __restrict__ gbase, int ld,
                                                   u16* lds, int tid) {
    int wid = tid >> 6;
#pragma unroll
    for (int i = 0; i < 4; ++i) {
        int idx = i * 256 + tid;            // 16B chunk index 0..1023
        int row = idx >> 3, c8 = idx & 7;
        int csw = c8 ^ (row & 7);           // pre-swizzled global source (m173 pattern)
        gld16(gbase + row * ld + csw * 8, lds + (i * 256 + wid * 64) * 8);  // wave-uniform LDS base
    }
}

static __device__ __forceinline__ bf16x8 frag(const u16* lds, int row, int col16) {
    return ld16(lds + row * 64 + ((col16 ^ (row & 7)) << 3));
}

// ---------------- GEMM1: qkv = xb(8192x512) @ wqkvT(1536x512)^T, scatter to Q/K/VT bf16 ----------------
__global__ __launch_bounds__(256) void k_gemm_qkv(const u16* __restrict__ xb, const u16* __restrict__ wT,
                                                  u16* __restrict__ Qh, u16* __restrict__ Kh,
                                                  u16* __restrict__ VTh) {
    __shared__ __align__(16) u16 at[128 * 64];
    __shared__ __align__(16) u16 bt[128 * 64];
    int tid = threadIdx.x, lane = tid & 63, wid = tid >> 6;
    int tm = blockIdx.x / 12, tn = blockIdx.x % 12;
    int rb = tm * 128, cb = tn * 128;
    int wr = (wid >> 1) * 64, wc = (wid & 1) * 64;
    int l15 = lane & 15, lhi = lane >> 4;
    f32x4 acc[4][4] = {};
    for (int kk = 0; kk < 512; kk += 64) {
        stage128x64(xb + rb * 512 + kk, 512, at, tid);
        stage128x64(wT + cb * 512 + kk, 512, bt, tid);
        __syncthreads();
        bf16x8 af[4][2], bfr[4][2];
#pragma unroll
        for (int m = 0; m < 4; ++m) {
            int row = wr + m * 16 + l15;
            af[m][0] = frag(at, row, lhi);
            af[m][1] = frag(at, row, 4 + lhi);
        }
#pragma unroll
        for (int n = 0; n < 4; ++n) {
            int row = wc + n * 16 + l15;
            bfr[n][0] = frag(bt, row, lhi);
            bfr[n][1] = frag(bt, row, 4 + lhi);
        }
#pragma unroll
        for (int m = 0; m < 4; ++m)
#pragma unroll
            for (int n = 0; n < 4; ++n) {
                acc[m][n] = mfma16(af[m][0], bfr[n][0], acc[m][n]);
                acc[m][n] = mfma16(af[m][1], bfr[n][1], acc[m][n]);
            }
        __syncthreads();
    }
#pragma unroll
    for (int m = 0; m < 4; ++m)
#pragma unroll
        for (int n = 0; n < 4; ++n)
#pragma unroll
            for (int r = 0; r < 4; ++r) {
                int R  = rb + wr + m * 16 + lhi * 4 + r;       // 0..8191 = b*2048+nseq
                int Cg = cb + wc + n * 16 + l15;               // 0..1535 = s*512 + h*64 + d
                int b = R >> 11, nseq = R & 2047;
                int s = Cg >> 9, rm = Cg & 511, h = rm >> 6, d = rm & 63;
                int bh = (b << 3) + h;
                u16 o = f2bf(acc[m][n][r]);
                if (s == 0)      Qh[(bh * 2048 + nseq) * 64 + d] = o;
                else if (s == 1) Kh[(bh * 2048 + nseq) * 64 + d] = o;
                else             VTh[(bh * 64 + d) * 2048 + nseq] = o;
            }
}

// ---------------- fused two-branch attention ----------------
// grid: 32 (b,h) * 32 q-tiles of 64; 4 waves/block, 16 queries/wave; no inter-wave sync.
__global__ __launch_bounds__(256) void k_attn(const u16* __restrict__ Qh, const u16* __restrict__ Kh,
                                              const u16* __restrict__ VTh, const float* __restrict__ alpha,
                                              const float* __restrict__ beta, u16* __restrict__ AO) {
    __shared__ __align__(16) u16 pe[4][16 * 32];   // per-wave P(dense) bf16 [16q][32keys]
    __shared__ __align__(16) u16 ps[4][16 * 32];   // per-wave P(sparse)
    int tid = threadIdx.x, lane = tid & 63, wid = tid >> 6;
    int l15 = lane & 15, lhi = lane >> 4;
    int bh = blockIdx.x >> 5;
    int qb = (blockIdx.x & 31) << 6;
    const u16* Qp = Qh + bh * (2048 * 64);
    const u16* Kp = Kh + bh * (2048 * 64);
    const u16* Vp = VTh + bh * (2048 * 64);
    u16* peL = pe[wid];
    u16* psL = ps[wid];
    int qrow = qb + wid * 16 + l15;
    bf16x8 qa0 = ld16(Qp + qrow * 64 + lhi * 8);        // d 0..31 fragment
    bf16x8 qa1 = ld16(Qp + qrow * 64 + 32 + lhi * 8);   // d 32..63
    f32x4 accd[4] = {}, accs[4] = {};
    float dend[4] = {0.f, 0.f, 0.f, 0.f};
    float dens[4] = {0.f, 0.f, 0.f, 0.f};
    const f32x4 z = {0.f, 0.f, 0.f, 0.f};
    for (int kb = 0; kb < 2048; kb += 32) {
        const u16* k0p = Kp + (kb + l15) * 64;
        const u16* k1p = Kp + (kb + 16 + l15) * 64;
        f32x4 s0 = mfma16(qa0, ld16(k0p + lhi * 8), z);
        s0       = mfma16(qa1, ld16(k0p + 32 + lhi * 8), s0);
        f32x4 s1 = mfma16(qa0, ld16(k1p + lhi * 8), z);
        s1       = mfma16(qa1, ld16(k1p + 32 + lhi * 8), s1);
#pragma unroll
        for (int r = 0; r < 4; ++r) {
            float a0 = s0[r] * 0.125f, a1 = s1[r] * 0.125f;   // scale = D^-0.5
            float e0 = __expf(a0), e1 = __expf(a1);           // no max-sub: |logit| <= ~7
            float p0 = a0 > 0.f ? a0 * a0 : 0.f;
            float p1 = a1 > 0.f ? a1 * a1 : 0.f;
            dend[r] += e0 + e1;
            dens[r] += p0 + p1;
            int prow = (lhi * 4 + r) * 32;
            peL[prow + l15]      = f2bf(e0);
            peL[prow + 16 + l15] = f2bf(e1);
            psL[prow + l15]      = f2bf(p0);
            psL[prow + 16 + l15] = f2bf(p1);
        }
        asm volatile("s_waitcnt lgkmcnt(0)" ::: "memory");
        bf16x8 ae = ld16(peL + l15 * 32 + lhi * 8);   // A-frag: m=query, k=key
        bf16x8 ap = ld16(psL + l15 * 32 + lhi * 8);
#pragma unroll
        for (int n = 0; n < 4; ++n) {
            bf16x8 bv = ld16(Vp + (n * 16 + l15) * 2048 + kb + lhi * 8);  // B[k=key][n=d] from VT
            accd[n] = mfma16(ae, bv, accd[n]);
            accs[n] = mfma16(ap, bv, accs[n]);
        }
        asm volatile("" ::: "memory");
    }
    // row-sum reduction across the 16 lanes sharing lhi
#pragma unroll
    for (int r = 0; r < 4; ++r) {
#pragma unroll
        for (int off = 1; off < 16; off <<= 1) {
            dend[r] += __shfl_xor(dend[r], off);
            dens[r] += __shfl_xor(dens[r], off);
        }
    }
    float sa = 1.f / (1.f + __expf(-alpha[0]));
    float sb = 1.f / (1.f + __expf(-beta[0]));
    float wsum = sa + sb + 1e-8f;
    float wa = sa / wsum, wb = sb / wsum;
    int b = bh >> 3, h = bh & 7;
#pragma unroll
    for (int n = 0; n < 4; ++n)
#pragma unroll
        for (int r = 0; r < 4; ++r) {
            int R  = b * 2048 + qb + wid * 16 + lhi * 4 + r;
            int Cg = h * 64 + n * 16 + l15;
            float o = wa * accs[n][r] / (dens[r] + 1e-8f) + wb * accd[n][r] / dend[r];
            AO[R * 512 + Cg] = f2bf(o);
        }
}

// ---------------- GEMM2: out = AO(8192x512) @ wprojT(512x512)^T + b_proj (f32 out) ----------------
__global__ __launch_bounds__(256) void k_gemm_proj(const u16* __restrict__ AO, const u16* __restrict__ wT,
                                                   const float* __restrict__ bproj, float* __restrict__ out) {
    __shared__ __align__(16) u16 at[128 * 64];
    __shared__ __align__(16) u16 bt[128 * 64];
    int tid = threadIdx.x, lane = tid & 63, wid = tid >> 6;
    int tm = blockIdx.x >> 2, tn = blockIdx.x & 3;
    int rb = tm * 128, cb = tn * 128;
    int wr = (wid >> 1) * 64, wc = (wid & 1) * 64;
    int l15 = lane & 15, lhi = lane >> 4;
    f32x4 acc[4][4] = {};
    for (int kk = 0; kk < 512; kk += 64) {
        stage128x64(AO + rb * 512 + kk, 512, at, tid);
        stage128x64(wT + cb * 512 + kk, 512, bt, tid);
        __syncthreads();
        bf16x8 af[4][2], bfr[4][2];
#pragma unroll
        for (int m = 0; m < 4; ++m) {
            int row = wr + m * 16 + l15;
            af[m][0] = frag(at, row, lhi);
            af[m][1] = frag(at, row, 4 + lhi);
        }
#pragma unroll
        for (int n = 0; n < 4; ++n) {
            int row = wc + n * 16 + l15;
            bfr[n][0] = frag(bt, row, lhi);
            bfr[n][1] = frag(bt, row, 4 + lhi);
        }
#pragma unroll
        for (int m = 0; m < 4; ++m)
#pragma unroll
            for (int n = 0; n < 4; ++n) {
                acc[m][n] = mfma16(af[m][0], bfr[n][0], acc[m][n]);
                acc[m][n] = mfma16(af[m][1], bfr[n][1], acc[m][n]);
            }
        __syncthreads();
    }
#pragma unroll
    for (int m = 0; m < 4; ++m)
#pragma unroll
        for (int n = 0; n < 4; ++n)
#pragma unroll
            for (int r = 0; r < 4; ++r) {
                int R  = rb + wr + m * 16 + lhi * 4 + r;
                int Cg = cb + wc + n * 16 + l15;
                out[R * 512 + Cg] = acc[m][n][r] + bproj[Cg];
            }
}

extern "C" void kernel_launch(void* const* d_in, const int* in_sizes, int n_in,
                              void* d_out, int out_size, void* d_ws, size_t ws_size,
                              hipStream_t stream) {
    const float* x      = (const float*)d_in[0];
    const float* w_qkv  = (const float*)d_in[1];
    const float* alpha  = (const float*)d_in[2];
    const float* beta   = (const float*)d_in[3];
    const float* w_proj = (const float*)d_in[4];
    const float* b_proj = (const float*)d_in[5];
    float* out = (float*)d_out;
    char* w = (char*)d_ws;
    // workspace layout (35,651,584 B total):
    u16* xb     = (u16*)(w);                 //  8,388,608 B  [8192][512] bf16
    u16* wqkvT  = (u16*)(w + 8388608);       //  1,572,864 B  [1536][512] bf16
    u16* wprojT = (u16*)(w + 9961472);       //    524,288 B  [512][512]  bf16
    u16* Qh     = (u16*)(w + 10485760);      //  8,388,608 B  [32][2048][64] bf16
    u16* Kh     = (u16*)(w + 18874368);      //  8,388,608 B
    u16* VTh    = (u16*)(w + 27262976);      //  8,388,608 B  [32][64][2048] bf16
    u16* AO     = xb;                        // alias: xb dead after k_gemm_qkv

    k_cast_x<<<dim3(4096), dim3(256), 0, stream>>>(x, xb);
    k_transpose_cast<<<dim3(48, 16), dim3(256), 0, stream>>>(w_qkv, wqkvT, 512, 1536);
    k_transpose_cast<<<dim3(16, 16), dim3(256), 0, stream>>>(w_proj, wprojT, 512, 512);
    k_gemm_qkv<<<dim3(768), dim3(256), 0, stream>>>(xb, wqkvT, Qh, Kh, VTh);
    k_attn<<<dim3(1024), dim3(256), 0, stream>>>(Qh, Kh, VTh, alpha, beta, AO);
    k_gemm_proj<<<dim3(256), dim3(256), 0, stream>>>(AO, wprojT, b_proj, out);
}

// Round 2
// 174.752 us; speedup vs baseline: 1.7209x; 1.7209x over previous
//
#include <hip/hip_runtime.h>

typedef unsigned short u16;
typedef unsigned int   u32;
typedef __attribute__((ext_vector_type(8))) __bf16 bf16x8;
typedef __attribute__((ext_vector_type(4))) float  f32x4;

#define AS1q __attribute__((address_space(1)))
#define AS3q __attribute__((address_space(3)))

static __device__ __forceinline__ u16 f2bf(float f) {
    u32 u = __builtin_bit_cast(u32, f);
    u32 r = u + 0x7FFFu + ((u >> 16) & 1u);   // round-to-nearest-even
    return (u16)(r >> 16);
}

static __device__ __forceinline__ bf16x8 ld16(const u16* p) {
    return __builtin_bit_cast(bf16x8, *(const float4*)(const void*)p);
}

static __device__ __forceinline__ f32x4 mfma16(bf16x8 a, bf16x8 b, f32x4 c) {
    return __builtin_amdgcn_mfma_f32_16x16x32_bf16(a, b, c, 0, 0, 0);
}

static __device__ __forceinline__ void gld16(const u16* g, u16* l) {
    __builtin_amdgcn_global_load_lds((const AS1q u32*)g, (AS3q u32*)l, 16, 0, 0);
}

// ---------------- cast x (f32) -> xb (bf16) ----------------
__global__ __launch_bounds__(256) void k_cast_x(const float* __restrict__ x, u16* __restrict__ xb) {
    int i = blockIdx.x * 256 + threadIdx.x;
    float4 v = ((const float4*)x)[i];
    ushort4 o;
    o.x = f2bf(v.x); o.y = f2bf(v.y); o.z = f2bf(v.z); o.w = f2bf(v.w);
    ((ushort4*)xb)[i] = o;
}

// ---------- transpose+cast: in[K][Nn] f32 -> out[Nn][K] bf16 ----------
__global__ __launch_bounds__(256) void k_transpose_cast(const float* __restrict__ in, u16* __restrict__ out,
                                                        int K, int Nn) {
    __shared__ float tile[32][33];
    int tx = threadIdx.x & 31, ty = threadIdx.x >> 5;
    int k0 = blockIdx.y * 32, n0 = blockIdx.x * 32;
#pragma unroll
    for (int i = 0; i < 4; ++i)
        tile[ty + i * 8][tx] = in[(k0 + ty + i * 8) * Nn + n0 + tx];
    __syncthreads();
#pragma unroll
    for (int i = 0; i < 4; ++i)
        out[(n0 + ty + i * 8) * K + k0 + tx] = f2bf(tile[tx][ty + i * 8]);
}

// ---------- shared GEMM pieces: 128x128 tile, BK=64, 4 waves (2x2), XOR-swizzled LDS ----------
static __device__ __forceinline__ void stage128x64(const u16* __restrict__ gbase, int ld,
                                                   u16* lds, int tid) {
    int wid = tid >> 6;
#pragma unroll
    for (int i = 0; i < 4; ++i) {
        int idx = i * 256 + tid;
        int row = idx >> 3, c8 = idx & 7;
        int csw = c8 ^ (row & 7);
        gld16(gbase + row * ld + csw * 8, lds + (i * 256 + wid * 64) * 8);
    }
}

static __device__ __forceinline__ bf16x8 frag(const u16* lds, int row, int col16) {
    return ld16(lds + row * 64 + ((col16 ^ (row & 7)) << 3));
}

// ---------------- GEMM1: qkv = xb @ wqkvT^T, scatter to Q/K/VT bf16 ----------------
__global__ __launch_bounds__(256) void k_gemm_qkv(const u16* __restrict__ xb, const u16* __restrict__ wT,
                                                  u16* __restrict__ Qh, u16* __restrict__ Kh,
                                                  u16* __restrict__ VTh) {
    __shared__ __align__(16) u16 at[128 * 64];
    __shared__ __align__(16) u16 bt[128 * 64];
    int tid = threadIdx.x, lane = tid & 63, wid = tid >> 6;
    int tm = blockIdx.x / 12, tn = blockIdx.x % 12;
    int rb = tm * 128, cb = tn * 128;
    int wr = (wid >> 1) * 64, wc = (wid & 1) * 64;
    int l15 = lane & 15, lhi = lane >> 4;
    f32x4 acc[4][4] = {};
    for (int kk = 0; kk < 512; kk += 64) {
        stage128x64(xb + rb * 512 + kk, 512, at, tid);
        stage128x64(wT + cb * 512 + kk, 512, bt, tid);
        __syncthreads();
        bf16x8 af[4][2], bfr[4][2];
#pragma unroll
        for (int m = 0; m < 4; ++m) {
            int row = wr + m * 16 + l15;
            af[m][0] = frag(at, row, lhi);
            af[m][1] = frag(at, row, 4 + lhi);
        }
#pragma unroll
        for (int n = 0; n < 4; ++n) {
            int row = wc + n * 16 + l15;
            bfr[n][0] = frag(bt, row, lhi);
            bfr[n][1] = frag(bt, row, 4 + lhi);
        }
#pragma unroll
        for (int m = 0; m < 4; ++m)
#pragma unroll
            for (int n = 0; n < 4; ++n) {
                acc[m][n] = mfma16(af[m][0], bfr[n][0], acc[m][n]);
                acc[m][n] = mfma16(af[m][1], bfr[n][1], acc[m][n]);
            }
        __syncthreads();
    }
#pragma unroll
    for (int m = 0; m < 4; ++m)
#pragma unroll
        for (int n = 0; n < 4; ++n)
#pragma unroll
            for (int r = 0; r < 4; ++r) {
                int R  = rb + wr + m * 16 + lhi * 4 + r;
                int Cg = cb + wc + n * 16 + l15;
                int b = R >> 11, nseq = R & 2047;
                int s = Cg >> 9, rm = Cg & 511, h = rm >> 6, d = rm & 63;
                int bh = (b << 3) + h;
                u16 o = f2bf(acc[m][n][r]);
                if (s == 0)      Qh[(bh * 2048 + nseq) * 64 + d] = o;
                else if (s == 1) Kh[(bh * 2048 + nseq) * 64 + d] = o;
                else             VTh[(bh * 64 + d) * 2048 + nseq] = o;
            }
}

// ---------------- fused two-branch attention v2 ----------------
// grid 512: T1-remapped -> bh (32) x qblock (16 of 128 q). 4 waves, 32 q/wave.
// K,VT double-buffered in LDS (global_load_lds, pre-swizzled source);
// P (dense+sparse) per-wave in LDS with chunk-XOR swizzle.
__global__ __launch_bounds__(256) void k_attn(const u16* __restrict__ Qh, const u16* __restrict__ Kh,
                                              const u16* __restrict__ VTh, const float* __restrict__ alpha,
                                              const float* __restrict__ beta, u16* __restrict__ AO) {
    __shared__ __align__(16) u16 kls[2][32 * 64];        // [buf][key][d], chunk c8 ^= key&7
    __shared__ __align__(16) u16 vls[2][64 * 32];        // [buf][d][key], chunk c4 ^= d&3
    __shared__ __align__(16) u16 pls[4][2][32 * 32];     // [wave][br][q][key], chunk c4 ^= q&3
    int tid = threadIdx.x, lane = tid & 63, wid = tid >> 6;
    int l15 = lane & 15, lhi = lane >> 4;
    int wg = (blockIdx.x & 7) * 64 + (blockIdx.x >> 3);  // XCD-aware swizzle (512 % 8 == 0)
    int bh = wg >> 4;
    int qb = (wg & 15) << 7;                             // 128 queries per block
    const u16* Qp = Qh + bh * (2048 * 64);
    const u16* Kp = Kh + bh * (2048 * 64);
    const u16* Vp = VTh + bh * (2048 * 64);
    // Q fragments resident: 2 m-tiles x 2 d-halves
    int qbase = qb + wid * 32;
    bf16x8 qa[2][2];
#pragma unroll
    for (int qm = 0; qm < 2; ++qm) {
        int row = qbase + qm * 16 + l15;
        qa[qm][0] = ld16(Qp + row * 64 + lhi * 8);
        qa[qm][1] = ld16(Qp + row * 64 + 32 + lhi * 8);
    }
    f32x4 accd[2][4] = {}, accs[2][4] = {};
    float dend[2][4] = {}, dens[2][4] = {};
    const f32x4 z = {0.f, 0.f, 0.f, 0.f};

    // staging lambdas: thread tid -> linear LDS 16B slot tid; global source pre-swizzled
    int krow = tid >> 3, kc8 = tid & 7;
    int vrow = tid >> 2, vc4 = tid & 3;
    const u16* kg = Kp + krow * 64 + ((kc8 ^ (krow & 7)) << 3);
    const u16* vg = Vp + vrow * 2048 + ((vc4 ^ (vrow & 3)) << 3);

    // prologue: stage chunk 0 into buf 0
    gld16(kg, &kls[0][0] + tid * 8);
    gld16(vg, &vls[0][0] + tid * 8);
    __syncthreads();

    for (int kb = 0; kb < 2048; kb += 32) {
        int cur = (kb >> 5) & 1;
        if (kb + 32 < 2048) {   // issue next-chunk stage early; latency hides under compute
            gld16(kg + (kb + 32) * 64, &kls[cur ^ 1][0] + tid * 8);
            gld16(vg + (kb + 32), &vls[cur ^ 1][0] + tid * 8);
        }
        // ---- S = Q K^T over this 32-key chunk ----
        f32x4 s[2][2];   // [qm][kt]
#pragma unroll
        for (int kt = 0; kt < 2; ++kt) {
            int row = kt * 16 + l15;
            bf16x8 kf0 = ld16(&kls[cur][0] + row * 64 + (((0 + lhi) ^ (row & 7)) << 3));
            bf16x8 kf1 = ld16(&kls[cur][0] + row * 64 + (((4 + lhi) ^ (row & 7)) << 3));
#pragma unroll
            for (int qm = 0; qm < 2; ++qm) {
                s[qm][kt] = mfma16(qa[qm][0], kf0, z);
                s[qm][kt] = mfma16(qa[qm][1], kf1, s[qm][kt]);
            }
        }
        // ---- pointwise: exp / relu^2, denominators, P -> LDS (bf16) ----
#pragma unroll
        for (int qm = 0; qm < 2; ++qm)
#pragma unroll
            for (int kt = 0; kt < 2; ++kt)
#pragma unroll
                for (int r = 0; r < 4; ++r) {
                    float v = s[qm][kt][r] * 0.125f;
                    float e = __expf(v);
                    float p = v > 0.f ? v * v : 0.f;
                    dend[qm][r] += e;
                    dens[qm][r] += p;
                    int q = qm * 16 + lhi * 4 + r;
                    int kcol = kt * 16 + l15;
                    int addr = q * 32 + (((kcol >> 3) ^ (q & 3)) << 3) + (kcol & 7);
                    pls[wid][0][addr] = f2bf(e);
                    pls[wid][1][addr] = f2bf(p);
                }
        asm volatile("s_waitcnt lgkmcnt(0)" ::: "memory");
        __builtin_amdgcn_sched_barrier(0);
        // ---- PV for both branches ----
        bf16x8 ae[2], ap[2];
#pragma unroll
        for (int qm = 0; qm < 2; ++qm) {
            int row = qm * 16 + l15;
            int off = row * 32 + (((lhi) ^ (row & 3)) << 3);
            ae[qm] = ld16(&pls[wid][0][off]);
            ap[qm] = ld16(&pls[wid][1][off]);
        }
#pragma unroll
        for (int n = 0; n < 4; ++n) {
            int row = n * 16 + l15;
            bf16x8 vf = ld16(&vls[cur][0] + row * 32 + ((lhi ^ (row & 3)) << 3));
#pragma unroll
            for (int qm = 0; qm < 2; ++qm) {
                accd[qm][n] = mfma16(ae[qm], vf, accd[qm][n]);
                accs[qm][n] = mfma16(ap[qm], vf, accs[qm][n]);
            }
        }
        __syncthreads();   // drains vmcnt too: next buffer staged & this buffer free
    }
    // ---- denominators: reduce across the 16 key-lanes ----
#pragma unroll
    for (int qm = 0; qm < 2; ++qm)
#pragma unroll
        for (int r = 0; r < 4; ++r) {
#pragma unroll
            for (int off = 1; off < 16; off <<= 1) {
                dend[qm][r] += __shfl_xor(dend[qm][r], off);
                dens[qm][r] += __shfl_xor(dens[qm][r], off);
            }
        }
    float sa = 1.f / (1.f + __expf(-alpha[0]));
    float sb = 1.f / (1.f + __expf(-beta[0]));
    float wsum = sa + sb + 1e-8f;
    float wa = sa / wsum, wb = sb / wsum;
    int b = bh >> 3, h = bh & 7;
#pragma unroll
    for (int qm = 0; qm < 2; ++qm)
#pragma unroll
        for (int n = 0; n < 4; ++n)
#pragma unroll
            for (int r = 0; r < 4; ++r) {
                int R  = b * 2048 + qbase + qm * 16 + lhi * 4 + r;
                int Cg = h * 64 + n * 16 + l15;
                float o = wa * accs[qm][n][r] / (dens[qm][r] + 1e-8f)
                        + wb * accd[qm][n][r] / dend[qm][r];
                AO[R * 512 + Cg] = f2bf(o);
            }
}

// ---------------- GEMM2: out = AO @ wprojT^T + b_proj (f32 out) ----------------
__global__ __launch_bounds__(256) void k_gemm_proj(const u16* __restrict__ AO, const u16* __restrict__ wT,
                                                   const float* __restrict__ bproj, float* __restrict__ out) {
    __shared__ __align__(16) u16 at[128 * 64];
    __shared__ __align__(16) u16 bt[128 * 64];
    int tid = threadIdx.x, lane = tid & 63, wid = tid >> 6;
    int tm = blockIdx.x >> 2, tn = blockIdx.x & 3;
    int rb = tm * 128, cb = tn * 128;
    int wr = (wid >> 1) * 64, wc = (wid & 1) * 64;
    int l15 = lane & 15, lhi = lane >> 4;
    f32x4 acc[4][4] = {};
    for (int kk = 0; kk < 512; kk += 64) {
        stage128x64(AO + rb * 512 + kk, 512, at, tid);
        stage128x64(wT + cb * 512 + kk, 512, bt, tid);
        __syncthreads();
        bf16x8 af[4][2], bfr[4][2];
#pragma unroll
        for (int m = 0; m < 4; ++m) {
            int row = wr + m * 16 + l15;
            af[m][0] = frag(at, row, lhi);
            af[m][1] = frag(at, row, 4 + lhi);
        }
#pragma unroll
        for (int n = 0; n < 4; ++n) {
            int row = wc + n * 16 + l15;
            bfr[n][0] = frag(bt, row, lhi);
            bfr[n][1] = frag(bt, row, 4 + lhi);
        }
#pragma unroll
        for (int m = 0; m < 4; ++m)
#pragma unroll
            for (int n = 0; n < 4; ++n) {
                acc[m][n] = mfma16(af[m][0], bfr[n][0], acc[m][n]);
                acc[m][n] = mfma16(af[m][1], bfr[n][1], acc[m][n]);
            }
        __syncthreads();
    }
#pragma unroll
    for (int m = 0; m < 4; ++m)
#pragma unroll
        for (int n = 0; n < 4; ++n)
#pragma unroll
            for (int r = 0; r < 4; ++r) {
                int R  = rb + wr + m * 16 + lhi * 4 + r;
                int Cg = cb + wc + n * 16 + l15;
                out[R * 512 + Cg] = acc[m][n][r] + bproj[Cg];
            }
}

extern "C" void kernel_launch(void* const* d_in, const int* in_sizes, int n_in,
                              void* d_out, int out_size, void* d_ws, size_t ws_size,
                              hipStream_t stream) {
    const float* x      = (const float*)d_in[0];
    const float* w_qkv  = (const float*)d_in[1];
    const float* alpha  = (const float*)d_in[2];
    const float* beta   = (const float*)d_in[3];
    const float* w_proj = (const float*)d_in[4];
    const float* b_proj = (const float*)d_in[5];
    float* out = (float*)d_out;
    char* w = (char*)d_ws;
    u16* xb     = (u16*)(w);                 //  8,388,608 B
    u16* wqkvT  = (u16*)(w + 8388608);       //  1,572,864 B
    u16* wprojT = (u16*)(w + 9961472);       //    524,288 B
    u16* Qh     = (u16*)(w + 10485760);      //  8,388,608 B
    u16* Kh     = (u16*)(w + 18874368);      //  8,388,608 B
    u16* VTh    = (u16*)(w + 27262976);      //  8,388,608 B
    u16* AO     = xb;                        // alias: xb dead after k_gemm_qkv

    k_cast_x<<<dim3(4096), dim3(256), 0, stream>>>(x, xb);
    k_transpose_cast<<<dim3(48, 16), dim3(256), 0, stream>>>(w_qkv, wqkvT, 512, 1536);
    k_transpose_cast<<<dim3(16, 16), dim3(256), 0, stream>>>(w_proj, wprojT, 512, 512);
    k_gemm_qkv<<<dim3(768), dim3(256), 0, stream>>>(xb, wqkvT, Qh, Kh, VTh);
    k_attn<<<dim3(512), dim3(256), 0, stream>>>(Qh, Kh, VTh, alpha, beta, AO);
    k_gemm_proj<<<dim3(256), dim3(256), 0, stream>>>(AO, wprojT, b_proj, out);
}

// Round 5
// 174.255 us; speedup vs baseline: 1.7258x; 1.0029x over previous
//
#include <hip/hip_runtime.h>

typedef unsigned short u16;
typedef unsigned int   u32;
typedef __attribute__((ext_vector_type(8))) __bf16 bf16x8;
typedef __attribute__((ext_vector_type(4))) float  f32x4;

#define AS1q __attribute__((address_space(1)))
#define AS3q __attribute__((address_space(3)))

static __device__ __forceinline__ u16 f2bf(float f) {
    u32 u = __builtin_bit_cast(u32, f);
    u32 r = u + 0x7FFFu + ((u >> 16) & 1u);   // round-to-nearest-even
    return (u16)(r >> 16);
}

static __device__ __forceinline__ bf16x8 ld16(const u16* p) {
    return __builtin_bit_cast(bf16x8, *(const float4*)(const void*)p);
}

static __device__ __forceinline__ f32x4 mfma16(bf16x8 a, bf16x8 b, f32x4 c) {
    return __builtin_amdgcn_mfma_f32_16x16x32_bf16(a, b, c, 0, 0, 0);
}

static __device__ __forceinline__ void gld16(const u16* g, u16* l) {
    __builtin_amdgcn_global_load_lds((const AS1q u32*)g, (AS3q u32*)l, 16, 0, 0);
}

// ---------------- cast x (f32) -> xb (bf16) ----------------
__global__ __launch_bounds__(256) void k_cast_x(const float* __restrict__ x, u16* __restrict__ xb) {
    int i = blockIdx.x * 256 + threadIdx.x;
    float4 v = ((const float4*)x)[i];
    ushort4 o;
    o.x = f2bf(v.x); o.y = f2bf(v.y); o.z = f2bf(v.z); o.w = f2bf(v.w);
    ((ushort4*)xb)[i] = o;
}

// ---------- transpose+cast: in[K][Nn] f32 -> out[Nn][K] bf16 ----------
__global__ __launch_bounds__(256) void k_transpose_cast(const float* __restrict__ in, u16* __restrict__ out,
                                                        int K, int Nn) {
    __shared__ float tile[32][33];
    int tx = threadIdx.x & 31, ty = threadIdx.x >> 5;
    int k0 = blockIdx.y * 32, n0 = blockIdx.x * 32;
#pragma unroll
    for (int i = 0; i < 4; ++i)
        tile[ty + i * 8][tx] = in[(k0 + ty + i * 8) * Nn + n0 + tx];
    __syncthreads();
#pragma unroll
    for (int i = 0; i < 4; ++i)
        out[(n0 + ty + i * 8) * K + k0 + tx] = f2bf(tile[tx][ty + i * 8]);
}

// ---------- shared GEMM pieces: 128x128 tile, BK=64, 4 waves (2x2), XOR-swizzled LDS ----------
static __device__ __forceinline__ void stage128x64(const u16* __restrict__ gbase, int ld,
                                                   u16* lds, int tid) {
    int wid = tid >> 6;
#pragma unroll
    for (int i = 0; i < 4; ++i) {
        int idx = i * 256 + tid;
        int row = idx >> 3, c8 = idx & 7;
        int csw = c8 ^ (row & 7);
        gld16(gbase + row * ld + csw * 8, lds + (i * 256 + wid * 64) * 8);
    }
}

static __device__ __forceinline__ bf16x8 frag(const u16* lds, int row, int col16) {
    return ld16(lds + row * 64 + ((col16 ^ (row & 7)) << 3));
}

// ---------------- GEMM1: qkv = xb @ wqkvT^T, scatter to Q/K/VT bf16 (Q pre-scaled by 0.125) ----------------
__global__ __launch_bounds__(256) void k_gemm_qkv(const u16* __restrict__ xb, const u16* __restrict__ wT,
                                                  u16* __restrict__ Qh, u16* __restrict__ Kh,
                                                  u16* __restrict__ VTh) {
    __shared__ __align__(16) u16 at[128 * 64];
    __shared__ __align__(16) u16 bt[128 * 64];
    int tid = threadIdx.x, lane = tid & 63, wid = tid >> 6;
    int tm = blockIdx.x / 12, tn = blockIdx.x % 12;
    int rb = tm * 128, cb = tn * 128;
    int wr = (wid >> 1) * 64, wc = (wid & 1) * 64;
    int l15 = lane & 15, lhi = lane >> 4;
    f32x4 acc[4][4] = {};
    for (int kk = 0; kk < 512; kk += 64) {
        stage128x64(xb + rb * 512 + kk, 512, at, tid);
        stage128x64(wT + cb * 512 + kk, 512, bt, tid);
        __syncthreads();
        bf16x8 af[4][2], bfr[4][2];
#pragma unroll
        for (int m = 0; m < 4; ++m) {
            int row = wr + m * 16 + l15;
            af[m][0] = frag(at, row, lhi);
            af[m][1] = frag(at, row, 4 + lhi);
        }
#pragma unroll
        for (int n = 0; n < 4; ++n) {
            int row = wc + n * 16 + l15;
            bfr[n][0] = frag(bt, row, lhi);
            bfr[n][1] = frag(bt, row, 4 + lhi);
        }
#pragma unroll
        for (int m = 0; m < 4; ++m)
#pragma unroll
            for (int n = 0; n < 4; ++n) {
                acc[m][n] = mfma16(af[m][0], bfr[n][0], acc[m][n]);
                acc[m][n] = mfma16(af[m][1], bfr[n][1], acc[m][n]);
            }
        __syncthreads();
    }
#pragma unroll
    for (int m = 0; m < 4; ++m)
#pragma unroll
        for (int n = 0; n < 4; ++n)
#pragma unroll
            for (int r = 0; r < 4; ++r) {
                int R  = rb + wr + m * 16 + lhi * 4 + r;
                int Cg = cb + wc + n * 16 + l15;
                int b = R >> 11, nseq = R & 2047;
                int s = Cg >> 9, rm = Cg & 511, h = rm >> 6, d = rm & 63;
                int bh = (b << 3) + h;
                float v = acc[m][n][r];
                if (s == 0)      Qh[(bh * 2048 + nseq) * 64 + d] = f2bf(v * 0.125f);  // fold D^-0.5
                else if (s == 1) Kh[(bh * 2048 + nseq) * 64 + d] = f2bf(v);
                else             VTh[(bh * 64 + d) * 2048 + nseq] = f2bf(v);
            }
}

// ---------------- fused two-branch attention (R2-verified structure, fixed P swizzle) ----------------
// grid 512: T1-remapped -> bh (32) x qblock (16 of 128 q). 4 waves, 32 q/wave.
// K,VT double-buffered in LDS (global_load_lds, pre-swizzled source);
// P (dense+sparse) per-wave in LDS, chunk-XOR key (q>>2)&3 (varies across lanes at write time).
__global__ __launch_bounds__(256) void k_attn(const u16* __restrict__ Qh, const u16* __restrict__ Kh,
                                              const u16* __restrict__ VTh, const float* __restrict__ alpha,
                                              const float* __restrict__ beta, u16* __restrict__ AO) {
    __shared__ __align__(16) u16 kls[2][32 * 64];        // [buf][key][d], chunk c8 ^= key&7
    __shared__ __align__(16) u16 vls[2][64 * 32];        // [buf][d][key], chunk c4 ^= d&3
    __shared__ __align__(16) u16 pls[4][2][32 * 32];     // [wave][br][q][key], chunk c4 ^= (q>>2)&3
    int tid = threadIdx.x, lane = tid & 63, wid = tid >> 6;
    int l15 = lane & 15, lhi = lane >> 4;
    int wg = (blockIdx.x & 7) * 64 + (blockIdx.x >> 3);  // XCD-aware swizzle (512 % 8 == 0)
    int bh = wg >> 4;
    int qb = (wg & 15) << 7;                             // 128 queries per block
    const u16* Qp = Qh + bh * (2048 * 64);
    const u16* Kp = Kh + bh * (2048 * 64);
    const u16* Vp = VTh + bh * (2048 * 64);
    int qbase = qb + wid * 32;
    bf16x8 qa[2][2];
#pragma unroll
    for (int qm = 0; qm < 2; ++qm) {
        int row = qbase + qm * 16 + l15;
        qa[qm][0] = ld16(Qp + row * 64 + lhi * 8);
        qa[qm][1] = ld16(Qp + row * 64 + 32 + lhi * 8);
    }
    f32x4 accd[2][4] = {}, accs[2][4] = {};
    float dend[2][4] = {}, dens[2][4] = {};
    const f32x4 z = {0.f, 0.f, 0.f, 0.f};

    int krow = tid >> 3, kc8 = tid & 7;
    int vrow = tid >> 2, vc4 = tid & 3;
    const u16* kg = Kp + krow * 64 + ((kc8 ^ (krow & 7)) << 3);   // pre-swizzled source
    const u16* vg = Vp + vrow * 2048 + ((vc4 ^ (vrow & 3)) << 3);

    gld16(kg, &kls[0][0] + tid * 8);
    gld16(vg, &vls[0][0] + tid * 8);
    __syncthreads();

    for (int kb = 0; kb < 2048; kb += 32) {
        int cur = (kb >> 5) & 1;
        if (kb + 32 < 2048) {   // issue next-chunk stage early; latency hides under compute
            gld16(kg + (kb + 32) * 64, &kls[cur ^ 1][0] + tid * 8);
            gld16(vg + (kb + 32), &vls[cur ^ 1][0] + tid * 8);
        }
        // ---- S = Q K^T over this 32-key chunk (Q pre-scaled, so S = logits) ----
        f32x4 s[2][2];   // [qm][kt]
#pragma unroll
        for (int kt = 0; kt < 2; ++kt) {
            int row = kt * 16 + l15;
            bf16x8 kf0 = ld16(&kls[cur][0] + row * 64 + (((0 + lhi) ^ (row & 7)) << 3));
            bf16x8 kf1 = ld16(&kls[cur][0] + row * 64 + (((4 + lhi) ^ (row & 7)) << 3));
#pragma unroll
            for (int qm = 0; qm < 2; ++qm) {
                s[qm][kt] = mfma16(qa[qm][0], kf0, z);
                s[qm][kt] = mfma16(qa[qm][1], kf1, s[qm][kt]);
            }
        }
        // ---- pointwise: exp / relu^2, denominators, P -> LDS (bf16) ----
#pragma unroll
        for (int qm = 0; qm < 2; ++qm)
#pragma unroll
            for (int kt = 0; kt < 2; ++kt)
#pragma unroll
                for (int r = 0; r < 4; ++r) {
                    float v = s[qm][kt][r];
                    float e = __expf(v);
                    float p = v > 0.f ? v * v : 0.f;
                    dend[qm][r] += e;
                    dens[qm][r] += p;
                    int q = qm * 16 + lhi * 4 + r;
                    int kcol = kt * 16 + l15;
                    int addr = q * 32 + (((kcol >> 3) ^ ((q >> 2) & 3)) << 3) + (kcol & 7);
                    pls[wid][0][addr] = f2bf(e);
                    pls[wid][1][addr] = f2bf(p);
                }
        asm volatile("s_waitcnt lgkmcnt(0)" ::: "memory");
        __builtin_amdgcn_sched_barrier(0);
        // ---- PV for both branches ----
        bf16x8 ae[2], ap[2];
#pragma unroll
        for (int qm = 0; qm < 2; ++qm) {
            int row = qm * 16 + l15;
            int off = row * 32 + ((lhi ^ ((row >> 2) & 3)) << 3);
            ae[qm] = ld16(&pls[wid][0][off]);
            ap[qm] = ld16(&pls[wid][1][off]);
        }
#pragma unroll
        for (int n = 0; n < 4; ++n) {
            int row = n * 16 + l15;
            bf16x8 vf = ld16(&vls[cur][0] + row * 32 + ((lhi ^ (row & 3)) << 3));
#pragma unroll
            for (int qm = 0; qm < 2; ++qm) {
                accd[qm][n] = mfma16(ae[qm], vf, accd[qm][n]);
                accs[qm][n] = mfma16(ap[qm], vf, accs[qm][n]);
            }
        }
        __syncthreads();   // drains vmcnt too: next buffer staged & this buffer free
    }
    // ---- denominators: reduce across the 16 key-lanes ----
#pragma unroll
    for (int qm = 0; qm < 2; ++qm)
#pragma unroll
        for (int r = 0; r < 4; ++r) {
#pragma unroll
            for (int off = 1; off < 16; off <<= 1) {
                dend[qm][r] += __shfl_xor(dend[qm][r], off);
                dens[qm][r] += __shfl_xor(dens[qm][r], off);
            }
        }
    float sa = 1.f / (1.f + __expf(-alpha[0]));
    float sb = 1.f / (1.f + __expf(-beta[0]));
    float wsum = sa + sb + 1e-8f;
    float wa = sa / wsum, wb = sb / wsum;
    int b = bh >> 3, h = bh & 7;
#pragma unroll
    for (int qm = 0; qm < 2; ++qm)
#pragma unroll
        for (int n = 0; n < 4; ++n)
#pragma unroll
            for (int r = 0; r < 4; ++r) {
                int R  = b * 2048 + qbase + qm * 16 + lhi * 4 + r;
                int Cg = h * 64 + n * 16 + l15;
                float o = wa * accs[qm][n][r] / (dens[qm][r] + 1e-8f)
                        + wb * accd[qm][n][r] / dend[qm][r];
                AO[R * 512 + Cg] = f2bf(o);
            }
}

// ---------------- GEMM2: out = AO @ wprojT^T + b_proj (f32 out) ----------------
__global__ __launch_bounds__(256) void k_gemm_proj(const u16* __restrict__ AO, const u16* __restrict__ wT,
                                                   const float* __restrict__ bproj, float* __restrict__ out) {
    __shared__ __align__(16) u16 at[128 * 64];
    __shared__ __align__(16) u16 bt[128 * 64];
    int tid = threadIdx.x, lane = tid & 63, wid = tid >> 6;
    int tm = blockIdx.x >> 2, tn = blockIdx.x & 3;
    int rb = tm * 128, cb = tn * 128;
    int wr = (wid >> 1) * 64, wc = (wid & 1) * 64;
    int l15 = lane & 15, lhi = lane >> 4;
    f32x4 acc[4][4] = {};
    for (int kk = 0; kk < 512; kk += 64) {
        stage128x64(AO + rb * 512 + kk, 512, at, tid);
        stage128x64(wT + cb * 512 + kk, 512, bt, tid);
        __syncthreads();
        bf16x8 af[4][2], bfr[4][2];
#pragma unroll
        for (int m = 0; m < 4; ++m) {
            int row = wr + m * 16 + l15;
            af[m][0] = frag(at, row, lhi);
            af[m][1] = frag(at, row, 4 + lhi);
        }
#pragma unroll
        for (int n = 0; n < 4; ++n) {
            int row = wc + n * 16 + l15;
            bfr[n][0] = frag(bt, row, lhi);
            bfr[n][1] = frag(bt, row, 4 + lhi);
        }
#pragma unroll
        for (int m = 0; m < 4; ++m)
#pragma unroll
            for (int n = 0; n < 4; ++n) {
                acc[m][n] = mfma16(af[m][0], bfr[n][0], acc[m][n]);
                acc[m][n] = mfma16(af[m][1], bfr[n][1], acc[m][n]);
            }
        __syncthreads();
    }
#pragma unroll
    for (int m = 0; m < 4; ++m)
#pragma unroll
        for (int n = 0; n < 4; ++n)
#pragma unroll
            for (int r = 0; r < 4; ++r) {
                int R  = rb + wr + m * 16 + lhi * 4 + r;
                int Cg = cb + wc + n * 16 + l15;
                out[R * 512 + Cg] = acc[m][n][r] + bproj[Cg];
            }
}

extern "C" void kernel_launch(void* const* d_in, const int* in_sizes, int n_in,
                              void* d_out, int out_size, void* d_ws, size_t ws_size,
                              hipStream_t stream) {
    const float* x      = (const float*)d_in[0];
    const float* w_qkv  = (const float*)d_in[1];
    const float* alpha  = (const float*)d_in[2];
    const float* beta   = (const float*)d_in[3];
    const float* w_proj = (const float*)d_in[4];
    const float* b_proj = (const float*)d_in[5];
    float* out = (float*)d_out;
    char* w = (char*)d_ws;
    u16* xb     = (u16*)(w);                 //  8,388,608 B
    u16* wqkvT  = (u16*)(w + 8388608);       //  1,572,864 B
    u16* wprojT = (u16*)(w + 9961472);       //    524,288 B
    u16* Qh     = (u16*)(w + 10485760);      //  8,388,608 B
    u16* Kh     = (u16*)(w + 18874368);      //  8,388,608 B
    u16* VTh    = (u16*)(w + 27262976);      //  8,388,608 B
    u16* AO     = xb;                        // alias: xb dead after k_gemm_qkv

    k_cast_x<<<dim3(4096), dim3(256), 0, stream>>>(x, xb);
    k_transpose_cast<<<dim3(48, 16), dim3(256), 0, stream>>>(w_qkv, wqkvT, 512, 1536);
    k_transpose_cast<<<dim3(16, 16), dim3(256), 0, stream>>>(w_proj, wprojT, 512, 512);
    k_gemm_qkv<<<dim3(768), dim3(256), 0, stream>>>(xb, wqkvT, Qh, Kh, VTh);
    k_attn<<<dim3(512), dim3(256), 0, stream>>>(Qh, Kh, VTh, alpha, beta, AO);
    k_gemm_proj<<<dim3(256), dim3(256), 0, stream>>>(AO, wprojT, b_proj, out);
}

// Round 6
// 168.050 us; speedup vs baseline: 1.7895x; 1.0369x over previous
//
#include <hip/hip_runtime.h>

typedef unsigned short u16;
typedef unsigned int   u32;
typedef __attribute__((ext_vector_type(8))) __bf16 bf16x8;
typedef __attribute__((ext_vector_type(4))) float  f32x4;

#define AS1q __attribute__((address_space(1)))
#define AS3q __attribute__((address_space(3)))

static __device__ __forceinline__ u16 f2bf(float f) {
    u32 u = __builtin_bit_cast(u32, f);
    u32 r = u + 0x7FFFu + ((u >> 16) & 1u);   // round-to-nearest-even
    return (u16)(r >> 16);
}

static __device__ __forceinline__ bf16x8 ld16(const u16* p) {
    return __builtin_bit_cast(bf16x8, *(const float4*)(const void*)p);
}

static __device__ __forceinline__ f32x4 mfma16(bf16x8 a, bf16x8 b, f32x4 c) {
    return __builtin_amdgcn_mfma_f32_16x16x32_bf16(a, b, c, 0, 0, 0);
}

static __device__ __forceinline__ void gld16(const u16* g, u16* l) {
    __builtin_amdgcn_global_load_lds((const AS1q u32*)g, (AS3q u32*)l, 16, 0, 0);
}

static __device__ __forceinline__ float exp2_fast(float v) {
    float e;
    asm("v_exp_f32 %0, %1" : "=v"(e) : "v"(v));
    return e;
}

// ---------------- cast x (f32) -> xb (bf16) ----------------
__global__ __launch_bounds__(256) void k_cast_x(const float* __restrict__ x, u16* __restrict__ xb) {
    int i = blockIdx.x * 256 + threadIdx.x;
    float4 v = ((const float4*)x)[i];
    ushort4 o;
    o.x = f2bf(v.x); o.y = f2bf(v.y); o.z = f2bf(v.z); o.w = f2bf(v.w);
    ((ushort4*)xb)[i] = o;
}

// ---------- transpose+cast: in[K][Nn] f32 -> out[Nn][K] bf16 ----------
__global__ __launch_bounds__(256) void k_transpose_cast(const float* __restrict__ in, u16* __restrict__ out,
                                                        int K, int Nn) {
    __shared__ float tile[32][33];
    int tx = threadIdx.x & 31, ty = threadIdx.x >> 5;
    int k0 = blockIdx.y * 32, n0 = blockIdx.x * 32;
#pragma unroll
    for (int i = 0; i < 4; ++i)
        tile[ty + i * 8][tx] = in[(k0 + ty + i * 8) * Nn + n0 + tx];
    __syncthreads();
#pragma unroll
    for (int i = 0; i < 4; ++i)
        out[(n0 + ty + i * 8) * K + k0 + tx] = f2bf(tile[tx][ty + i * 8]);
}

// ---------- shared GEMM pieces: 128x128 tile, BK=64, 4 waves (2x2), XOR-swizzled LDS ----------
static __device__ __forceinline__ void stage128x64(const u16* __restrict__ gbase, int ld,
                                                   u16* lds, int tid) {
    int wid = tid >> 6;
#pragma unroll
    for (int i = 0; i < 4; ++i) {
        int idx = i * 256 + tid;
        int row = idx >> 3, c8 = idx & 7;
        int csw = c8 ^ (row & 7);
        gld16(gbase + row * ld + csw * 8, lds + (i * 256 + wid * 64) * 8);
    }
}

static __device__ __forceinline__ bf16x8 frag(const u16* lds, int row, int col16) {
    return ld16(lds + row * 64 + ((col16 ^ (row & 7)) << 3));
}

// ---------------- GEMM1: qkv = xb @ wqkvT^T, scatter to Q/K/VT bf16 ----------------
// Q pre-scaled by 0.125*log2(e): dense branch uses exp2 directly; sparse branch is scale-invariant.
__global__ __launch_bounds__(256) void k_gemm_qkv(const u16* __restrict__ xb, const u16* __restrict__ wT,
                                                  u16* __restrict__ Qh, u16* __restrict__ Kh,
                                                  u16* __restrict__ VTh) {
    __shared__ __align__(16) u16 at[128 * 64];
    __shared__ __align__(16) u16 bt[128 * 64];
    int tid = threadIdx.x, lane = tid & 63, wid = tid >> 6;
    int tm = blockIdx.x / 12, tn = blockIdx.x % 12;
    int rb = tm * 128, cb = tn * 128;
    int wr = (wid >> 1) * 64, wc = (wid & 1) * 64;
    int l15 = lane & 15, lhi = lane >> 4;
    f32x4 acc[4][4] = {};
    for (int kk = 0; kk < 512; kk += 64) {
        stage128x64(xb + rb * 512 + kk, 512, at, tid);
        stage128x64(wT + cb * 512 + kk, 512, bt, tid);
        __syncthreads();
        bf16x8 af[4][2], bfr[4][2];
#pragma unroll
        for (int m = 0; m < 4; ++m) {
            int row = wr + m * 16 + l15;
            af[m][0] = frag(at, row, lhi);
            af[m][1] = frag(at, row, 4 + lhi);
        }
#pragma unroll
        for (int n = 0; n < 4; ++n) {
            int row = wc + n * 16 + l15;
            bfr[n][0] = frag(bt, row, lhi);
            bfr[n][1] = frag(bt, row, 4 + lhi);
        }
#pragma unroll
        for (int m = 0; m < 4; ++m)
#pragma unroll
            for (int n = 0; n < 4; ++n) {
                acc[m][n] = mfma16(af[m][0], bfr[n][0], acc[m][n]);
                acc[m][n] = mfma16(af[m][1], bfr[n][1], acc[m][n]);
            }
        __syncthreads();
    }
#pragma unroll
    for (int m = 0; m < 4; ++m)
#pragma unroll
        for (int n = 0; n < 4; ++n)
#pragma unroll
            for (int r = 0; r < 4; ++r) {
                int R  = rb + wr + m * 16 + lhi * 4 + r;
                int Cg = cb + wc + n * 16 + l15;
                int b = R >> 11, nseq = R & 2047;
                int s = Cg >> 9, rm = Cg & 511, h = rm >> 6, d = rm & 63;
                int bh = (b << 3) + h;
                float v = acc[m][n][r];
                if (s == 0)      Qh[(bh * 2048 + nseq) * 64 + d] = f2bf(v * 0.1803368801111244f);
                else if (s == 1) Kh[(bh * 2048 + nseq) * 64 + d] = f2bf(v);
                else             VTh[(bh * 64 + d) * 2048 + nseq] = f2bf(v);
            }
}

// ---------------- fused two-branch attention v5 (64 q/block, grid 1024) ----------------
// 4 waves x 16 q/wave. K,VT double-buffered in LDS (global_load_lds, pre-swizzled source);
// P (dense+sparse) per-wave in LDS. Occupancy: 4 blocks/CU (24 KB LDS).
__global__ __launch_bounds__(256) void k_attn(const u16* __restrict__ Qh, const u16* __restrict__ Kh,
                                              const u16* __restrict__ VTh, const float* __restrict__ alpha,
                                              const float* __restrict__ beta, u16* __restrict__ AO) {
    __shared__ __align__(16) u16 kls[2][32 * 64];        // [buf][key][d], chunk c8 ^= key&7
    __shared__ __align__(16) u16 vls[2][64 * 32];        // [buf][d][key], chunk c4 ^= d&3
    __shared__ __align__(16) u16 pls[4][2][16 * 32];     // [wave][br][q][key], chunk c4 ^= q>>2
    int tid = threadIdx.x, lane = tid & 63, wid = tid >> 6;
    int l15 = lane & 15, lhi = lane >> 4;
    int wg = (blockIdx.x & 7) * 128 + (blockIdx.x >> 3);  // XCD-aware swizzle (1024 % 8 == 0)
    int bh = wg >> 5;
    int qb = (wg & 31) << 6;                              // 64 queries per block
    const u16* Qp = Qh + bh * (2048 * 64);
    const u16* Kp = Kh + bh * (2048 * 64);
    const u16* Vp = VTh + bh * (2048 * 64);
    int qbase = qb + wid * 16;
    bf16x8 qa0 = ld16(Qp + (qbase + l15) * 64 + lhi * 8);
    bf16x8 qa1 = ld16(Qp + (qbase + l15) * 64 + 32 + lhi * 8);
    f32x4 accd[4] = {}, accs[4] = {};
    float dend[4] = {}, dens[4] = {};
    const f32x4 z = {0.f, 0.f, 0.f, 0.f};

    int krow = tid >> 3, kc8 = tid & 7;
    int vrow = tid >> 2, vc4 = tid & 3;
    const u16* kg = Kp + krow * 64 + ((kc8 ^ (krow & 7)) << 3);   // pre-swizzled source
    const u16* vg = Vp + vrow * 2048 + ((vc4 ^ (vrow & 3)) << 3);

    gld16(kg, &kls[0][0] + tid * 8);
    gld16(vg, &vls[0][0] + tid * 8);
    __syncthreads();

    for (int kb = 0; kb < 2048; kb += 32) {
        int cur = (kb >> 5) & 1;
        if (kb + 32 < 2048) {   // issue next-chunk stage early; latency hides under compute
            gld16(kg + (kb + 32) * 64, &kls[cur ^ 1][0] + tid * 8);
            gld16(vg + (kb + 32), &vls[cur ^ 1][0] + tid * 8);
        }
        // ---- S = Q K^T over this 32-key chunk (Q pre-scaled by 0.125*log2e) ----
        f32x4 s[2];
#pragma unroll
        for (int kt = 0; kt < 2; ++kt) {
            int row = kt * 16 + l15;
            bf16x8 kf0 = ld16(&kls[cur][0] + row * 64 + ((lhi ^ (row & 7)) << 3));
            bf16x8 kf1 = ld16(&kls[cur][0] + row * 64 + (((4 + lhi) ^ (row & 7)) << 3));
            s[kt] = mfma16(qa0, kf0, z);
            s[kt] = mfma16(qa1, kf1, s[kt]);
        }
        // ---- pointwise: exp2 / relu^2, denominators, P -> LDS (bf16) ----
#pragma unroll
        for (int kt = 0; kt < 2; ++kt)
#pragma unroll
            for (int r = 0; r < 4; ++r) {
                float v = s[kt][r];
                float e = exp2_fast(v);
                float t = fmaxf(v, 0.f);
                float p = t * t;
                dend[r] += e;
                dens[r] += p;
                int q = lhi * 4 + r;
                int kcol = kt * 16 + l15;
                int addr = q * 32 + (((kcol >> 3) ^ lhi) << 3) + (kcol & 7);
                pls[wid][0][addr] = f2bf(e);
                pls[wid][1][addr] = f2bf(p);
            }
        asm volatile("s_waitcnt lgkmcnt(0)" ::: "memory");
        __builtin_amdgcn_sched_barrier(0);
        // ---- PV for both branches ----
        int off = l15 * 32 + ((lhi ^ ((l15 >> 2) & 3)) << 3);
        bf16x8 ae = ld16(&pls[wid][0][off]);
        bf16x8 ap = ld16(&pls[wid][1][off]);
#pragma unroll
        for (int n = 0; n < 4; ++n) {
            int row = n * 16 + l15;
            bf16x8 vf = ld16(&vls[cur][0] + row * 32 + ((lhi ^ (row & 3)) << 3));
            accd[n] = mfma16(ae, vf, accd[n]);
            accs[n] = mfma16(ap, vf, accs[n]);
        }
        __syncthreads();   // drains vmcnt too: next buffer staged & this buffer free
    }
    // ---- denominators: reduce across the 16 key-lanes ----
#pragma unroll
    for (int r = 0; r < 4; ++r) {
#pragma unroll
        for (int off = 1; off < 16; off <<= 1) {
            dend[r] += __shfl_xor(dend[r], off);
            dens[r] += __shfl_xor(dens[r], off);
        }
    }
    float sa = 1.f / (1.f + __expf(-alpha[0]));
    float sb = 1.f / (1.f + __expf(-beta[0]));
    float wsum = sa + sb + 1e-8f;
    float wa = sa / wsum, wb = sb / wsum;
    int b = bh >> 3, h = bh & 7;
#pragma unroll
    for (int n = 0; n < 4; ++n)
#pragma unroll
        for (int r = 0; r < 4; ++r) {
            int R  = b * 2048 + qbase + lhi * 4 + r;
            int Cg = h * 64 + n * 16 + l15;
            float o = wa * accs[n][r] / (dens[r] + 1e-8f)
                    + wb * accd[n][r] / dend[r];
            AO[R * 512 + Cg] = f2bf(o);
        }
}

// ---------------- GEMM2: out = AO @ wprojT^T + b_proj (f32 out) ----------------
__global__ __launch_bounds__(256) void k_gemm_proj(const u16* __restrict__ AO, const u16* __restrict__ wT,
                                                   const float* __restrict__ bproj, float* __restrict__ out) {
    __shared__ __align__(16) u16 at[128 * 64];
    __shared__ __align__(16) u16 bt[128 * 64];
    int tid = threadIdx.x, lane = tid & 63, wid = tid >> 6;
    int tm = blockIdx.x >> 2, tn = blockIdx.x & 3;
    int rb = tm * 128, cb = tn * 128;
    int wr = (wid >> 1) * 64, wc = (wid & 1) * 64;
    int l15 = lane & 15, lhi = lane >> 4;
    f32x4 acc[4][4] = {};
    for (int kk = 0; kk < 512; kk += 64) {
        stage128x64(AO + rb * 512 + kk, 512, at, tid);
        stage128x64(wT + cb * 512 + kk, 512, bt, tid);
        __syncthreads();
        bf16x8 af[4][2], bfr[4][2];
#pragma unroll
        for (int m = 0; m < 4; ++m) {
            int row = wr + m * 16 + l15;
            af[m][0] = frag(at, row, lhi);
            af[m][1] = frag(at, row, 4 + lhi);
        }
#pragma unroll
        for (int n = 0; n < 4; ++n) {
            int row = wc + n * 16 + l15;
            bfr[n][0] = frag(bt, row, lhi);
            bfr[n][1] = frag(bt, row, 4 + lhi);
        }
#pragma unroll
        for (int m = 0; m < 4; ++m)
#pragma unroll
            for (int n = 0; n < 4; ++n) {
                acc[m][n] = mfma16(af[m][0], bfr[n][0], acc[m][n]);
                acc[m][n] = mfma16(af[m][1], bfr[n][1], acc[m][n]);
            }
        __syncthreads();
    }
#pragma unroll
    for (int m = 0; m < 4; ++m)
#pragma unroll
        for (int n = 0; n < 4; ++n)
#pragma unroll
            for (int r = 0; r < 4; ++r) {
                int R  = rb + wr + m * 16 + lhi * 4 + r;
                int Cg = cb + wc + n * 16 + l15;
                out[R * 512 + Cg] = acc[m][n][r] + bproj[Cg];
            }
}

extern "C" void kernel_launch(void* const* d_in, const int* in_sizes, int n_in,
                              void* d_out, int out_size, void* d_ws, size_t ws_size,
                              hipStream_t stream) {
    const float* x      = (const float*)d_in[0];
    const float* w_qkv  = (const float*)d_in[1];
    const float* alpha  = (const float*)d_in[2];
    const float* beta   = (const float*)d_in[3];
    const float* w_proj = (const float*)d_in[4];
    const float* b_proj = (const float*)d_in[5];
    float* out = (float*)d_out;
    char* w = (char*)d_ws;
    u16* xb     = (u16*)(w);                 //  8,388,608 B
    u16* wqkvT  = (u16*)(w + 8388608);       //  1,572,864 B
    u16* wprojT = (u16*)(w + 9961472);       //    524,288 B
    u16* Qh     = (u16*)(w + 10485760);      //  8,388,608 B
    u16* Kh     = (u16*)(w + 18874368);      //  8,388,608 B
    u16* VTh    = (u16*)(w + 27262976);      //  8,388,608 B
    u16* AO     = xb;                        // alias: xb dead after k_gemm_qkv

    k_cast_x<<<dim3(4096), dim3(256), 0, stream>>>(x, xb);
    k_transpose_cast<<<dim3(48, 16), dim3(256), 0, stream>>>(w_qkv, wqkvT, 512, 1536);
    k_transpose_cast<<<dim3(16, 16), dim3(256), 0, stream>>>(w_proj, wprojT, 512, 512);
    k_gemm_qkv<<<dim3(768), dim3(256), 0, stream>>>(xb, wqkvT, Qh, Kh, VTh);
    k_attn<<<dim3(1024), dim3(256), 0, stream>>>(Qh, Kh, VTh, alpha, beta, AO);
    k_gemm_proj<<<dim3(256), dim3(256), 0, stream>>>(AO, wprojT, b_proj, out);
}